// Round 8
// baseline (121.535 us; speedup 1.0000x reference)
//
#include <hip/hip_runtime.h>

// K-winners-take-all: per row of [4096, 8192] f32, exactly k=410 largest -> 1.0.
// Ties at the k-th value broken by LOWER index (jax.lax.top_k stable semantics).
//
// R8: software-pipelined rows. Each block owns 4 consecutive rows, 512 threads,
// two register buffers (kvA/kvB, 4 x uint4 each). Row r+1's loads are issued
// before row r is processed; the freed buffer is reloaded immediately after its
// write-phase VALU reads (store operands are separate temps, so no store-ack
// gate on the reload). All 1024 blocks co-resident (4/CU) -> loads of one row
// overlap selection+stores of the previous everywhere. R7 post-mortem: phases
// were serial (load ~15us + select ~8us + store ~21us = 44us observed); this
// hides the load phase for 3 of 4 rows.
// Selection per row (unchanged from R7): 512-bin monotone histogram of
// bits > 1.5f, per-wave redundant suffix-scan + shfl-max broadcast,
// (key,index) clist in threshold bin, winner = lex-rank < kkb.
// Exact fallbacks kept (never taken on N(0,1)): f2ord block radix + eqmask.

#define E      8192
#define BLK    512
#define PER    4            // uint4 per thread per row
#define ROWS   4            // rows per block
#define KACT   410
#define NBINS  512
#define SHIFTB 15
#define BASEB  0x3FC00000u  // bits of 1.5f
#define CCAP   64

typedef float f32x4 __attribute__((ext_vector_type(4)));

struct Sm {
    unsigned hist[NBINS];    // 2 KB
    unsigned clk[CCAP];
    unsigned cli[CCAP];
    unsigned eqmask[BLK];    // fallback only
    unsigned wsum[8];        // fallback only
    unsigned cnum, prefix, kk;
};

__device__ __forceinline__ unsigned f2ord(unsigned u) {
    return (u & 0x80000000u) ? ~u : (u | 0x80000000u);
}

// fallback-only: rank of equal-element (it,j) of thread t among all equals.
// element index e = (it*BLK + t)*4 + j ; eqmask[t'] bit (it'*4+j') marks equals.
__device__ __noinline__ unsigned eq_rank(const unsigned* eqmask, int t, int it, int j) {
    const unsigned m_lt = (2u << (4 * it + 3)) - 1u;
    const unsigned m_eq = (1u << (4 * it + j)) - 1u;
    const unsigned m_gt = (1u << (4 * it)) - 1u;
    unsigned cnt = 0;
    for (int tp = 0; tp < BLK; ++tp) {
        unsigned em = eqmask[tp];
        unsigned msk = (tp < t) ? m_lt : ((tp == t) ? m_eq : m_gt);
        cnt += __popc(em & msk);
    }
    return cnt;
}

// cold exact path: 4x8-bit radix over f2ord keys + eqmask tie-break
__device__ __noinline__ void fallback_row(uint4 (&kv)[PER], float* outp, Sm& sm,
                                          int t, int lane) {
    #pragma unroll 1
    for (int p = 0; p < 4; ++p) {
        const int shift = 24 - 8 * p;
        const unsigned fixedmask = (p == 0) ? 0u : (0xFFFFFFFFu << (shift + 8));
        if (t < 256) sm.hist[t] = 0u;
        __syncthreads();
        const unsigned pref = sm.prefix;
        #pragma unroll
        for (int it = 0; it < PER; ++it) {
            uint4 v = kv[it];
            unsigned a[4] = {v.x, v.y, v.z, v.w};
            #pragma unroll
            for (int j = 0; j < 4; ++j) {
                unsigned key = f2ord(a[j]);
                if ((key & fixedmask) == pref)
                    atomicAdd(&sm.hist[(key >> shift) & 255u], 1u);
            }
        }
        __syncthreads();
        if (t < 64) {
            const int b4 = t * 4;
            unsigned h0 = sm.hist[b4], h1 = sm.hist[b4 + 1];
            unsigned h2 = sm.hist[b4 + 2], h3 = sm.hist[b4 + 3];
            unsigned local2 = h0 + h1 + h2 + h3;
            unsigned run2 = local2;
            #pragma unroll
            for (int d = 1; d < 64; d <<= 1) {
                unsigned o = __shfl_down(run2, d);
                run2 += (lane + d < 64) ? o : 0u;
            }
            const unsigned tail2 = run2 - local2;
            const unsigned kk = sm.kk;
            const unsigned s3 = tail2 + h3;
            const unsigned s2 = s3 + h2;
            const unsigned s1 = s2 + h1;
            const unsigned s0 = s1 + h0;
            if      (s0 >= kk && s1    < kk) { sm.prefix = pref | ((unsigned)(b4 + 0) << shift); sm.kk = kk - s1; }
            else if (s1 >= kk && s2    < kk) { sm.prefix = pref | ((unsigned)(b4 + 1) << shift); sm.kk = kk - s2; }
            else if (s2 >= kk && s3    < kk) { sm.prefix = pref | ((unsigned)(b4 + 2) << shift); sm.kk = kk - s3; }
            else if (s3 >= kk && tail2 < kk) { sm.prefix = pref | ((unsigned)(b4 + 3) << shift); sm.kk = kk - tail2; }
        }
        __syncthreads();
    }
    const unsigned T = sm.prefix, kkT = sm.kk;

    unsigned myeq = 0u;
    #pragma unroll
    for (int it = 0; it < PER; ++it) {
        uint4 v = kv[it];
        unsigned a[4] = {v.x, v.y, v.z, v.w};
        #pragma unroll
        for (int j = 0; j < 4; ++j)
            myeq |= (f2ord(a[j]) == T ? 1u : 0u) << (it * 4 + j);
    }
    sm.eqmask[t] = myeq;
    unsigned pm = __popc(myeq);
    #pragma unroll
    for (int d = 1; d < 64; d <<= 1) pm += __shfl_down(pm, d);
    if (lane == 0) sm.wsum[t >> 6] = pm;
    __syncthreads();
    unsigned m = 0;
    #pragma unroll
    for (int w = 0; w < 8; ++w) m += sm.wsum[w];
    const bool allwin = (kkT == m);

    f32x4* o = reinterpret_cast<f32x4*>(outp);
    #pragma unroll
    for (int it = 0; it < PER; ++it) {
        uint4 v = kv[it];
        unsigned a[4] = {v.x, v.y, v.z, v.w};
        float rs[4];
        #pragma unroll
        for (int j = 0; j < 4; ++j) {
            unsigned key = f2ord(a[j]);
            float val;
            if (key > T)       val = 1.0f;
            else if (key != T) val = 0.0f;
            else if (allwin)   val = 1.0f;
            else               val = (eq_rank(sm.eqmask, t, it, j) < kkT) ? 1.0f : 0.0f;
            rs[j] = val;
        }
        f32x4 rr; rr.x = rs[0]; rr.y = rs[1]; rr.z = rs[2]; rr.w = rs[3];
        __builtin_nontemporal_store(rr, o + it * BLK + t);
    }
    __syncthreads();   // protect sm reuse by next row against stragglers
}

__device__ __forceinline__ void process_row(uint4 (&kv)[PER], float* outp, Sm& sm,
                                            int t, int lane) {
    // zero phase (safe vs previous row: first clk/cli write is after this B0,
    // so all threads have left the previous write loop by then)
    if (t < NBINS) sm.hist[t] = 0u;
    if (t == 0) { sm.cnum = 0u; sm.prefix = 0u; sm.kk = KACT; }
    __syncthreads();                                            // B0

    // histogram candidates (> 1.5) from registers
    #pragma unroll
    for (int it = 0; it < PER; ++it) {
        uint4 v = kv[it];
        unsigned a[4] = {v.x, v.y, v.z, v.w};
        #pragma unroll
        for (int j = 0; j < 4; ++j) {
            if (__uint_as_float(a[j]) > 1.5f) {
                unsigned bb = (a[j] - BASEB) >> SHIFTB;
                bb = (bb > NBINS - 1u) ? (NBINS - 1u) : bb;
                atomicAdd(&sm.hist[bb], 1u);
            }
        }
    }
    __syncthreads();                                            // B1

    // per-wave full suffix-scan of all 512 bins (redundant per wave)
    unsigned h[8]; unsigned local = 0;
    #pragma unroll
    for (int j2 = 0; j2 < 8; ++j2) { h[j2] = sm.hist[8 * lane + j2]; local += h[j2]; }
    unsigned run = local;
    #pragma unroll
    for (int d = 1; d < 64; d <<= 1) {
        unsigned o = __shfl_down(run, d);
        run += (lane + d < 64) ? o : 0u;
    }
    const unsigned total = __shfl(run, 0);
    const unsigned tail  = run - local;
    unsigned bsel = 0, kkb = 0;
    {
        unsigned suf = tail;
        #pragma unroll
        for (int j2 = 7; j2 >= 0; --j2) {
            if (suf < KACT && suf + h[j2] >= KACT) { bsel = 8u * lane + j2; kkb = KACT - suf; }
            suf += h[j2];
        }
    }
    unsigned packed = kkb ? ((bsel << 16) | kkb) : 0u;   // exactly one lane nonzero
    #pragma unroll
    for (int d = 1; d < 64; d <<= 1) {
        unsigned o = __shfl_xor(packed, d);
        packed = (o > packed) ? o : packed;
    }
    bsel = packed >> 16; kkb = packed & 0xFFFFu;

    bool fb = (total < KACT);

    const unsigned binlo = BASEB + (bsel << SHIFTB);
    const float binlo_f = __uint_as_float(binlo);
    const float binhi_f = (bsel == NBINS - 1u) ? __uint_as_float(0x7F800000u)
                                               : __uint_as_float(binlo + (1u << SHIFTB));

    // collect threshold-bin (key, index) pairs
    if (!fb) {
        #pragma unroll
        for (int it = 0; it < PER; ++it) {
            uint4 v = kv[it];
            unsigned a[4] = {v.x, v.y, v.z, v.w};
            #pragma unroll
            for (int j = 0; j < 4; ++j) {
                float xf = __uint_as_float(a[j]);
                if (xf >= binlo_f && xf < binhi_f && xf > 1.5f) {
                    unsigned p = atomicAdd(&sm.cnum, 1u);
                    if (p < CCAP) { sm.clk[p] = a[j]; sm.cli[p] = (unsigned)((it * BLK + t) * 4 + j); }
                }
            }
        }
    }
    __syncthreads();                                            // B2
    const unsigned cn = sm.cnum;
    if (cn > CCAP) fb = true;

    if (!fb) {
        // fast path: winners = (x >= binhi) | (in-bin lex-rank < kkb)
        f32x4* o = reinterpret_cast<f32x4*>(outp);
        #pragma unroll
        for (int it = 0; it < PER; ++it) {
            uint4 v = kv[it];
            unsigned a[4] = {v.x, v.y, v.z, v.w};
            float rs[4];
            #pragma unroll
            for (int j = 0; j < 4; ++j) {
                unsigned key = a[j];
                float xf = __uint_as_float(key);
                float val;
                if (xf >= binhi_f) val = 1.0f;
                else if (xf >= binlo_f) {
                    unsigned idx = (unsigned)((it * BLK + t) * 4 + j);
                    unsigned rank = 0;
                    for (unsigned q = 0; q < cn; ++q) {
                        unsigned kq = sm.clk[q];
                        rank += (kq > key || (kq == key && sm.cli[q] < idx)) ? 1u : 0u;
                    }
                    val = (rank < kkb) ? 1.0f : 0.0f;
                } else val = 0.0f;
                rs[j] = val;
            }
            f32x4 rr; rr.x = rs[0]; rr.y = rs[1]; rr.z = rs[2]; rr.w = rs[3];
            __builtin_nontemporal_store(rr, o + it * BLK + t);
        }
    } else {
        fallback_row(kv, outp, sm, t, lane);
    }
}

#define LOAD_ROW(buf, rowidx)                                               \
    {                                                                       \
        const uint4* xin_ = reinterpret_cast<const uint4*>(x + (size_t)(rowidx) * E); \
        _Pragma("unroll")                                                   \
        for (int it_ = 0; it_ < PER; ++it_) buf[it_] = xin_[it_ * BLK + t]; \
    }

__global__ __launch_bounds__(BLK, 8)
void kwta_kernel(const float* __restrict__ x, float* __restrict__ out) {
    __shared__ Sm sm;
    const int t    = threadIdx.x;
    const int lane = t & 63;
    const size_t r0 = (size_t)blockIdx.x * ROWS;

    uint4 kvA[PER], kvB[PER];

    LOAD_ROW(kvA, r0 + 0);
    LOAD_ROW(kvB, r0 + 1);                      // in flight during row 0

    process_row(kvA, out + (r0 + 0) * E, sm, t, lane);
    LOAD_ROW(kvA, r0 + 2);                      // in flight during row 1

    process_row(kvB, out + (r0 + 1) * E, sm, t, lane);
    LOAD_ROW(kvB, r0 + 3);                      // in flight during row 2

    process_row(kvA, out + (r0 + 2) * E, sm, t, lane);
    process_row(kvB, out + (r0 + 3) * E, sm, t, lane);
}

extern "C" void kernel_launch(void* const* d_in, const int* in_sizes, int n_in,
                              void* d_out, int out_size, void* d_ws, size_t ws_size,
                              hipStream_t stream) {
    const float* x = (const float*)d_in[0];
    float* out = (float*)d_out;
    const int rows = in_sizes[0] / E;           // 4096
    kwta_kernel<<<dim3(rows / ROWS), dim3(BLK), 0, stream>>>(x, out);
}

// Round 9
// 82.108 us; speedup vs baseline: 1.4802x; 1.4802x over previous
//
#include <hip/hip_runtime.h>

// K-winners-take-all: per row of [4096, 8192] f32, exactly k=410 largest -> 1.0.
// Ties at the k-th value broken by LOWER index (jax.lax.top_k stable semantics).
//
// R9: pipelined rows WITHOUT register spill (R8's failure = array-by-reference
// into a noinline fn -> scratch round-trip; fixed by pointer-taking fallbacks
// and by compressing per-row state to 8-bit bin codes).
// Per block: 4 consecutive rows, 512 threads, ONE full-row buffer (4 x uint4).
// Per row: hist+codes (bins 1..255 monotone over bits>1.5f; 0 = non-candidate)
//   -> per-wave redundant suffix scan (total, threshold bin bsel, kkb)
//   -> collect in-bin (key,idx) from still-live buffer
//   -> PREFETCH next row into the freed buffer   <- overlaps scan/write phases
//   -> barrier -> write mask from codes (in-bin resolved exactly via clist).
// The top bin (255) merges all x >= ~5.97 but is resolved exactly by value, so
// the merge is semantically lossless. Exact cold paths (never on N(0,1)):
// total<k, or in-bin pile-up > CCAP -> pointer-based radix fallback.

#define E      8192
#define BLK    512
#define PER    4            // uint4 per thread per row
#define ROWS   4            // rows per block; 4096/4 = 1024 blocks = fully resident
#define KACT   410
#define NBINS  256
#define SHIFTB 16
#define BASEB  0x3FC00000u  // bits of 1.5f
#define CCAP   64

typedef float f32x4 __attribute__((ext_vector_type(4)));

struct Sm {
    unsigned hist[NBINS];    // 1 KB (also radix hist in fallback)
    unsigned clk[CCAP];
    unsigned cli[CCAP];
    unsigned eqmask[BLK];    // fallback only (2 KB)
    unsigned wsum[8];        // fallback only
    unsigned cnum, prefix, kk;
};

__device__ __forceinline__ unsigned f2ord(unsigned u) {
    return (u & 0x80000000u) ? ~u : (u | 0x80000000u);
}

// fallback-only: rank of equal-element (it,j) of thread t among all equals.
__device__ __noinline__ unsigned eq_rank(const unsigned* eqmask, int t, int it, int j) {
    const unsigned m_lt = (2u << (4 * it + 3)) - 1u;
    const unsigned m_eq = (1u << (4 * it + j)) - 1u;
    const unsigned m_gt = (1u << (4 * it)) - 1u;
    unsigned cnt = 0;
    for (int tp = 0; tp < BLK; ++tp) {
        unsigned em = eqmask[tp];
        unsigned msk = (tp < t) ? m_lt : ((tp == t) ? m_eq : m_gt);
        cnt += __popc(em & msk);
    }
    return cnt;
}

// cold exact path. Takes POINTERS only (no array by-reference: R8 lesson --
// byref arrays go to scratch). Loads its own copy of the row.
__device__ __noinline__ void fallback_row(const float* __restrict__ xrow,
                                          float* __restrict__ outp, Sm& sm,
                                          int t, int lane) {
    const uint4* xin = reinterpret_cast<const uint4*>(xrow);
    uint4 kv[PER];
    #pragma unroll
    for (int it = 0; it < PER; ++it) kv[it] = xin[it * BLK + t];
    if (t == 0) { sm.prefix = 0u; sm.kk = KACT; }

    #pragma unroll 1
    for (int p = 0; p < 4; ++p) {
        const int shift = 24 - 8 * p;
        const unsigned fixedmask = (p == 0) ? 0u : (0xFFFFFFFFu << (shift + 8));
        if (t < 256) sm.hist[t] = 0u;
        __syncthreads();
        const unsigned pref = sm.prefix;
        #pragma unroll
        for (int it = 0; it < PER; ++it) {
            uint4 v = kv[it];
            unsigned a[4] = {v.x, v.y, v.z, v.w};
            #pragma unroll
            for (int j = 0; j < 4; ++j) {
                unsigned key = f2ord(a[j]);
                if ((key & fixedmask) == pref)
                    atomicAdd(&sm.hist[(key >> shift) & 255u], 1u);
            }
        }
        __syncthreads();
        if (t < 64) {
            const int b4 = t * 4;
            unsigned h0 = sm.hist[b4], h1 = sm.hist[b4 + 1];
            unsigned h2 = sm.hist[b4 + 2], h3 = sm.hist[b4 + 3];
            unsigned local2 = h0 + h1 + h2 + h3;
            unsigned run2 = local2;
            #pragma unroll
            for (int d = 1; d < 64; d <<= 1) {
                unsigned o = __shfl_down(run2, d);
                run2 += (lane + d < 64) ? o : 0u;
            }
            const unsigned tail2 = run2 - local2;
            const unsigned kk = sm.kk;
            const unsigned s3 = tail2 + h3;
            const unsigned s2 = s3 + h2;
            const unsigned s1 = s2 + h1;
            const unsigned s0 = s1 + h0;
            if      (s0 >= kk && s1    < kk) { sm.prefix = pref | ((unsigned)(b4 + 0) << shift); sm.kk = kk - s1; }
            else if (s1 >= kk && s2    < kk) { sm.prefix = pref | ((unsigned)(b4 + 1) << shift); sm.kk = kk - s2; }
            else if (s2 >= kk && s3    < kk) { sm.prefix = pref | ((unsigned)(b4 + 2) << shift); sm.kk = kk - s3; }
            else if (s3 >= kk && tail2 < kk) { sm.prefix = pref | ((unsigned)(b4 + 3) << shift); sm.kk = kk - tail2; }
        }
        __syncthreads();
    }
    const unsigned T = sm.prefix, kkT = sm.kk;

    unsigned myeq = 0u;
    #pragma unroll
    for (int it = 0; it < PER; ++it) {
        uint4 v = kv[it];
        unsigned a[4] = {v.x, v.y, v.z, v.w};
        #pragma unroll
        for (int j = 0; j < 4; ++j)
            myeq |= (f2ord(a[j]) == T ? 1u : 0u) << (it * 4 + j);
    }
    sm.eqmask[t] = myeq;
    unsigned pm = __popc(myeq);
    #pragma unroll
    for (int d = 1; d < 64; d <<= 1) pm += __shfl_down(pm, d);
    if (lane == 0) sm.wsum[t >> 6] = pm;
    __syncthreads();
    unsigned m = 0;
    #pragma unroll
    for (int w = 0; w < 8; ++w) m += sm.wsum[w];
    const bool allwin = (kkT == m);

    f32x4* o = reinterpret_cast<f32x4*>(outp);
    #pragma unroll
    for (int it = 0; it < PER; ++it) {
        uint4 v = kv[it];
        unsigned a[4] = {v.x, v.y, v.z, v.w};
        float rs[4];
        #pragma unroll
        for (int j = 0; j < 4; ++j) {
            unsigned key = f2ord(a[j]);
            float val;
            if (key > T)       val = 1.0f;
            else if (key != T) val = 0.0f;
            else if (allwin)   val = 1.0f;
            else               val = (eq_rank(sm.eqmask, t, it, j) < kkT) ? 1.0f : 0.0f;
            rs[j] = val;
        }
        f32x4 rr; rr.x = rs[0]; rr.y = rs[1]; rr.z = rs[2]; rr.w = rs[3];
        __builtin_nontemporal_store(rr, o + it * BLK + t);
    }
    __syncthreads();   // protect sm reuse by caller's next row
}

__global__ __launch_bounds__(BLK, 8)
void kwta_kernel(const float* __restrict__ x, float* __restrict__ out) {
    __shared__ Sm sm;
    const int t    = threadIdx.x;
    const int lane = t & 63;
    const size_t r0 = (size_t)blockIdx.x * ROWS;

    uint4 buf[PER];
    {
        const uint4* xin = reinterpret_cast<const uint4*>(x + r0 * E);
        #pragma unroll
        for (int it = 0; it < PER; ++it) buf[it] = xin[it * BLK + t];
    }

    #pragma unroll 1
    for (int row = 0; row < ROWS; ++row) {
        const size_t rowbase = (r0 + row) * (size_t)E;
        if (t < NBINS) sm.hist[t] = 0u;
        if (t == 0) sm.cnum = 0u;
        __syncthreads();                                        // B0

        // ---- histogram + 8-bit codes (1..255 candidates, 0 otherwise) ----
        unsigned codes[PER];
        #pragma unroll
        for (int it = 0; it < PER; ++it) {
            uint4 v = buf[it];
            unsigned a[4] = {v.x, v.y, v.z, v.w};
            unsigned cw = 0;
            #pragma unroll
            for (int j = 0; j < 4; ++j) {
                unsigned code = 0;
                if (__uint_as_float(a[j]) > 1.5f) {
                    unsigned bb = (a[j] - BASEB) >> SHIFTB;
                    bb = (bb > 254u) ? 254u : bb;   // top bin merged; resolved exactly below
                    code = bb + 1u;
                    atomicAdd(&sm.hist[code], 1u);
                }
                cw |= code << (8 * j);
            }
            codes[it] = cw;
        }
        __syncthreads();                                        // B1

        // ---- per-wave redundant suffix scan over 256 bins ----
        unsigned h[4]; unsigned local = 0;
        #pragma unroll
        for (int j2 = 0; j2 < 4; ++j2) { h[j2] = sm.hist[4 * lane + j2]; local += h[j2]; }
        unsigned run = local;
        #pragma unroll
        for (int d = 1; d < 64; d <<= 1) {
            unsigned o = __shfl_down(run, d);
            run += (lane + d < 64) ? o : 0u;
        }
        const unsigned total = __shfl(run, 0);
        const unsigned tail  = run - local;
        unsigned bsel = 0, kkb = 0;
        {
            unsigned suf = tail;
            #pragma unroll
            for (int j2 = 3; j2 >= 0; --j2) {
                if (suf < KACT && suf + h[j2] >= KACT) { bsel = 4u * lane + j2; kkb = KACT - suf; }
                suf += h[j2];
            }
        }
        unsigned packed = kkb ? ((bsel << 16) | kkb) : 0u;   // exactly one lane nonzero
        #pragma unroll
        for (int d = 1; d < 64; d <<= 1) {
            unsigned o = __shfl_xor(packed, d);
            packed = (o > packed) ? o : packed;
        }
        bsel = packed >> 16; kkb = packed & 0xFFFFu;

        if (total < KACT) {   // block-uniform cold path: threshold could be <= 1.5
            fallback_row(x + rowbase, out + rowbase, sm, t, lane);
            if (row + 1 < ROWS) {
                const uint4* xin = reinterpret_cast<const uint4*>(x + (r0 + row + 1) * E);
                #pragma unroll
                for (int it = 0; it < PER; ++it) buf[it] = xin[it * BLK + t];
            }
            continue;
        }

        // ---- collect in-bin (key, idx) from the still-live buffer ----
        #pragma unroll
        for (int it = 0; it < PER; ++it) {
            unsigned cw = codes[it];
            uint4 v = buf[it];
            unsigned a[4] = {v.x, v.y, v.z, v.w};
            #pragma unroll
            for (int j = 0; j < 4; ++j) {
                if (((cw >> (8 * j)) & 255u) == bsel) {
                    unsigned p = atomicAdd(&sm.cnum, 1u);
                    if (p < CCAP) { sm.clk[p] = a[j]; sm.cli[p] = (unsigned)((it * BLK + t) * 4 + j); }
                }
            }
        }
        // ---- prefetch next row into the freed buffer (overlaps write phase) ----
        if (row + 1 < ROWS) {
            const uint4* xin = reinterpret_cast<const uint4*>(x + (r0 + row + 1) * E);
            #pragma unroll
            for (int it = 0; it < PER; ++it) buf[it] = xin[it * BLK + t];
        }
        __syncthreads();                                        // B2
        const unsigned cn = sm.cnum;
        if (cn > CCAP) {      // block-uniform: adversarial pile-up -> exact path
            fallback_row(x + rowbase, out + rowbase, sm, t, lane);
            if (row + 1 < ROWS) {   // re-issue (buf was dead across the call)
                const uint4* xin = reinterpret_cast<const uint4*>(x + (r0 + row + 1) * E);
                #pragma unroll
                for (int it = 0; it < PER; ++it) buf[it] = xin[it * BLK + t];
            }
            continue;
        }

        // ---- write mask from codes ----
        f32x4* o = reinterpret_cast<f32x4*>(out + rowbase);
        #pragma unroll
        for (int it = 0; it < PER; ++it) {
            unsigned cw = codes[it];
            float rs[4];
            #pragma unroll
            for (int j = 0; j < 4; ++j) {
                unsigned code = (cw >> (8 * j)) & 255u;
                float val;
                if (code > bsel)      val = 1.0f;
                else if (code < bsel) val = 0.0f;
                else {
                    // in threshold bin (~10-15 elements/row): exact lex-rank
                    unsigned idx = (unsigned)((it * BLK + t) * 4 + j);
                    unsigned key = 0, rank = 0;
                    for (unsigned q = 0; q < cn; ++q)
                        if (sm.cli[q] == idx) key = sm.clk[q];
                    for (unsigned q = 0; q < cn; ++q) {
                        unsigned kq = sm.clk[q];
                        rank += (kq > key || (kq == key && sm.cli[q] < idx)) ? 1u : 0u;
                    }
                    val = (rank < kkb) ? 1.0f : 0.0f;
                }
                rs[j] = val;
            }
            f32x4 rr; rr.x = rs[0]; rr.y = rs[1]; rr.z = rs[2]; rr.w = rs[3];
            __builtin_nontemporal_store(rr, o + it * BLK + t);
        }
        // no trailing barrier needed: next row's first clk/cli write is after
        // its B1; hist zeroing (pre-B0) touches no array read in this phase.
    }
}

extern "C" void kernel_launch(void* const* d_in, const int* in_sizes, int n_in,
                              void* d_out, int out_size, void* d_ws, size_t ws_size,
                              hipStream_t stream) {
    const float* x = (const float*)d_in[0];
    float* out = (float*)d_out;
    const int rows = in_sizes[0] / E;           // 4096
    kwta_kernel<<<dim3(rows / ROWS), dim3(BLK), 0, stream>>>(x, out);
}

// Round 10
// 69.345 us; speedup vs baseline: 1.7526x; 1.1841x over previous
//
#include <hip/hip_runtime.h>

// K-winners-take-all: per row of [4096, 8192] f32, exactly k=410 largest -> 1.0.
// Ties at the k-th value broken by LOWER index (jax.lax.top_k stable semantics).
//
// R10 = R9 pipelined structure with the two codegen bugs fixed:
//  (a) NO function calls (R9's noinline fallback call forced call-ABI VGPR=32 +
//      scratch; R7 proved inline-everything compiles clean at 28 VGPR).
//  (b) RAW barriers in the hot path: __syncthreads() emits s_waitcnt vmcnt(0)
//      before s_barrier (drains all global loads -> prefetch dies). We need only
//      LDS ordering at block barriers, so: s_waitcnt lgkmcnt(0); s_barrier.
//      The next-row register prefetch then stays in flight across the write
//      phase (compiler emits a counted vmcnt before its first use).
// Per block: 4 consecutive rows, 512 threads, one row buffer (4 x uint4) +
// 8-bit monotone bin codes per element. Per row: hist+codes -> per-wave
// redundant suffix scan -> collect in-bin (key,idx) -> prefetch next row ->
// B2 -> write mask from codes (in-bin exact via clist lex-rank).
// Cold exact paths (never on N(0,1) data) fully inline: f2ord radix + eqmask.

#define E      8192
#define BLK    512
#define PER    4            // uint4 per thread per row
#define ROWS   4            // 4096/4 = 1024 blocks = fully resident at (512,8)
#define KACT   410
#define NBINS  256
#define SHIFTB 16
#define BASEB  0x3FC00000u  // bits of 1.5f
#define CCAP   64

typedef float f32x4 __attribute__((ext_vector_type(4)));

struct Sm {
    unsigned hist[NBINS];    // 1 KB (also radix hist in fallback)
    unsigned clk[CCAP];
    unsigned cli[CCAP];
    unsigned eqmask[BLK];    // fallback only (2 KB)
    unsigned wsum[8];        // fallback only
    unsigned cnum, prefix, kk;
};

// LDS-only barrier: waits LDS ops, leaves global loads/stores in flight.
// (plain __syncthreads drains vmcnt(0) -> kills cross-row prefetch)
#define BAR_LDS() do {                                         \
    asm volatile("s_waitcnt lgkmcnt(0)" ::: "memory");         \
    __builtin_amdgcn_sched_barrier(0);                         \
    __builtin_amdgcn_s_barrier();                              \
    __builtin_amdgcn_sched_barrier(0);                         \
    asm volatile("" ::: "memory");                             \
} while (0)

__device__ __forceinline__ unsigned f2ord(unsigned u) {
    return (u & 0x80000000u) ? ~u : (u | 0x80000000u);
}

__global__ __launch_bounds__(BLK, 8)
void kwta_kernel(const float* __restrict__ x, float* __restrict__ out) {
    __shared__ Sm sm;
    const int t    = threadIdx.x;
    const int lane = t & 63;
    const size_t r0 = (size_t)blockIdx.x * ROWS;

    uint4 buf[PER];
    {
        const uint4* xin = reinterpret_cast<const uint4*>(x + r0 * E);
        #pragma unroll
        for (int it = 0; it < PER; ++it) buf[it] = xin[it * BLK + t];
    }

    #pragma unroll 1
    for (int row = 0; row < ROWS; ++row) {
        const size_t rowbase = (r0 + row) * (size_t)E;

        if (t < NBINS) sm.hist[t] = 0u;
        BAR_LDS();                                              // B0

        // ---- codes (1..255 candidates, 0 otherwise) + histogram ----
        unsigned codes[PER];
        #pragma unroll
        for (int it = 0; it < PER; ++it) {
            uint4 v = buf[it];
            unsigned a[4] = {v.x, v.y, v.z, v.w};
            unsigned cw = 0;
            #pragma unroll
            for (int j = 0; j < 4; ++j) {
                unsigned code = 0;
                if (__uint_as_float(a[j]) > 1.5f) {
                    unsigned bb = (a[j] - BASEB) >> SHIFTB;
                    bb = (bb > 254u) ? 254u : bb;   // top bin merged; exact below
                    code = bb + 1u;
                    atomicAdd(&sm.hist[code], 1u);
                }
                cw |= code << (8 * j);
            }
            codes[it] = cw;
        }
        if (t == 0) sm.cnum = 0u;   // collect atomics are after B1: race-free
        BAR_LDS();                                              // B1

        // ---- per-wave redundant suffix scan over 256 bins ----
        unsigned h[4]; unsigned local = 0;
        #pragma unroll
        for (int j2 = 0; j2 < 4; ++j2) { h[j2] = sm.hist[4 * lane + j2]; local += h[j2]; }
        unsigned run = local;
        #pragma unroll
        for (int d = 1; d < 64; d <<= 1) {
            unsigned o = __shfl_down(run, d);
            run += (lane + d < 64) ? o : 0u;
        }
        const unsigned total = __shfl(run, 0);
        const unsigned tail  = run - local;
        unsigned bsel = 0, kkb = 0;
        {
            unsigned suf = tail;
            #pragma unroll
            for (int j2 = 3; j2 >= 0; --j2) {
                if (suf < KACT && suf + h[j2] >= KACT) { bsel = 4u * lane + j2; kkb = KACT - suf; }
                suf += h[j2];
            }
        }
        unsigned packed = kkb ? ((bsel << 16) | kkb) : 0u;   // one lane nonzero
        #pragma unroll
        for (int d = 1; d < 64; d <<= 1) {
            unsigned o = __shfl_xor(packed, d);
            packed = (o > packed) ? o : packed;
        }
        bsel = packed >> 16; kkb = packed & 0xFFFFu;

        bool need_fb = (total < KACT);   // block-uniform
        if (!need_fb) {
            // ---- collect in-bin (key, idx) from still-live buffer ----
            #pragma unroll
            for (int it = 0; it < PER; ++it) {
                unsigned cw = codes[it];
                uint4 v = buf[it];
                unsigned a[4] = {v.x, v.y, v.z, v.w};
                #pragma unroll
                for (int j = 0; j < 4; ++j) {
                    if (((cw >> (8 * j)) & 255u) == bsel) {
                        unsigned p = atomicAdd(&sm.cnum, 1u);
                        if (p < CCAP) { sm.clk[p] = a[j]; sm.cli[p] = (unsigned)((it * BLK + t) * 4 + j); }
                    }
                }
            }
            // ---- prefetch next row; survives B2 + write phase (raw barriers) ----
            if (row + 1 < ROWS) {
                const uint4* xin = reinterpret_cast<const uint4*>(x + (r0 + row + 1) * E);
                #pragma unroll
                for (int it = 0; it < PER; ++it) buf[it] = xin[it * BLK + t];
            }
            BAR_LDS();                                          // B2
            const unsigned cn = sm.cnum;
            if (cn <= CCAP) {
                // ---- write mask from codes ----
                f32x4* o = reinterpret_cast<f32x4*>(out + rowbase);
                #pragma unroll
                for (int it = 0; it < PER; ++it) {
                    unsigned cw = codes[it];
                    float rs[4];
                    #pragma unroll
                    for (int j = 0; j < 4; ++j) {
                        unsigned code = (cw >> (8 * j)) & 255u;
                        float val;
                        if (code > bsel)      val = 1.0f;
                        else if (code < bsel) val = 0.0f;
                        else {
                            unsigned idx = (unsigned)((it * BLK + t) * 4 + j);
                            unsigned key = 0, rank = 0;
                            for (unsigned q = 0; q < cn; ++q)
                                if (sm.cli[q] == idx) key = sm.clk[q];
                            for (unsigned q = 0; q < cn; ++q) {
                                unsigned kq = sm.clk[q];
                                rank += (kq > key || (kq == key && sm.cli[q] < idx)) ? 1u : 0u;
                            }
                            val = (rank < kkb) ? 1.0f : 0.0f;
                        }
                        rs[j] = val;
                    }
                    f32x4 rr; rr.x = rs[0]; rr.y = rs[1]; rr.z = rs[2]; rr.w = rs[3];
                    __builtin_nontemporal_store(rr, o + it * BLK + t);
                }
            } else {
                need_fb = true;   // block-uniform (cn same everywhere)
            }
        }

        if (need_fb) {
            // ======== COLD exact path, fully inline (no calls: R9 lesson) ======
            __syncthreads();   // protect hist from any in-flight scan reads
            {   // reload current row (buf may hold the prefetched next row)
                const uint4* xin = reinterpret_cast<const uint4*>(x + rowbase);
                #pragma unroll
                for (int it = 0; it < PER; ++it) buf[it] = xin[it * BLK + t];
            }
            if (t == 0) { sm.prefix = 0u; sm.kk = KACT; }

            #pragma unroll 1
            for (int p = 0; p < 4; ++p) {
                const int shift = 24 - 8 * p;
                const unsigned fixedmask = (p == 0) ? 0u : (0xFFFFFFFFu << (shift + 8));
                if (t < 256) sm.hist[t] = 0u;
                __syncthreads();
                const unsigned pref = sm.prefix;
                #pragma unroll
                for (int it = 0; it < PER; ++it) {
                    uint4 v = buf[it];
                    unsigned a[4] = {v.x, v.y, v.z, v.w};
                    #pragma unroll
                    for (int j = 0; j < 4; ++j) {
                        unsigned key = f2ord(a[j]);
                        if ((key & fixedmask) == pref)
                            atomicAdd(&sm.hist[(key >> shift) & 255u], 1u);
                    }
                }
                __syncthreads();
                if (t < 64) {
                    const int b4 = t * 4;
                    unsigned h0 = sm.hist[b4], h1 = sm.hist[b4 + 1];
                    unsigned h2 = sm.hist[b4 + 2], h3 = sm.hist[b4 + 3];
                    unsigned local2 = h0 + h1 + h2 + h3;
                    unsigned run2 = local2;
                    #pragma unroll
                    for (int d = 1; d < 64; d <<= 1) {
                        unsigned o = __shfl_down(run2, d);
                        run2 += (lane + d < 64) ? o : 0u;
                    }
                    const unsigned tail2 = run2 - local2;
                    const unsigned kk = sm.kk;
                    const unsigned s3 = tail2 + h3;
                    const unsigned s2 = s3 + h2;
                    const unsigned s1 = s2 + h1;
                    const unsigned s0 = s1 + h0;
                    if      (s0 >= kk && s1    < kk) { sm.prefix = pref | ((unsigned)(b4 + 0) << shift); sm.kk = kk - s1; }
                    else if (s1 >= kk && s2    < kk) { sm.prefix = pref | ((unsigned)(b4 + 1) << shift); sm.kk = kk - s2; }
                    else if (s2 >= kk && s3    < kk) { sm.prefix = pref | ((unsigned)(b4 + 2) << shift); sm.kk = kk - s3; }
                    else if (s3 >= kk && tail2 < kk) { sm.prefix = pref | ((unsigned)(b4 + 3) << shift); sm.kk = kk - tail2; }
                }
                __syncthreads();
            }
            const unsigned T = sm.prefix, kkT = sm.kk;

            unsigned myeq = 0u;
            #pragma unroll
            for (int it = 0; it < PER; ++it) {
                uint4 v = buf[it];
                unsigned a[4] = {v.x, v.y, v.z, v.w};
                #pragma unroll
                for (int j = 0; j < 4; ++j)
                    myeq |= (f2ord(a[j]) == T ? 1u : 0u) << (it * 4 + j);
            }
            sm.eqmask[t] = myeq;
            unsigned pm = __popc(myeq);
            #pragma unroll
            for (int d = 1; d < 64; d <<= 1) pm += __shfl_down(pm, d);
            if (lane == 0) sm.wsum[t >> 6] = pm;
            __syncthreads();
            unsigned m = 0;
            #pragma unroll
            for (int w = 0; w < 8; ++w) m += sm.wsum[w];
            const bool allwin = (kkT == m);

            f32x4* o = reinterpret_cast<f32x4*>(out + rowbase);
            #pragma unroll
            for (int it = 0; it < PER; ++it) {
                uint4 v = buf[it];
                unsigned a[4] = {v.x, v.y, v.z, v.w};
                float rs[4];
                #pragma unroll
                for (int j = 0; j < 4; ++j) {
                    unsigned key = f2ord(a[j]);
                    float val;
                    if (key > T)       val = 1.0f;
                    else if (key != T) val = 0.0f;
                    else if (allwin)   val = 1.0f;
                    else {
                        // exact index-ordered rank among equals (any m)
                        const unsigned m_lt = (2u << (4 * it + 3)) - 1u;
                        const unsigned m_eq = (1u << (4 * it + j)) - 1u;
                        const unsigned m_gt = (1u << (4 * it)) - 1u;
                        unsigned cnt = 0;
                        for (int tp = 0; tp < BLK; ++tp) {
                            unsigned em = sm.eqmask[tp];
                            unsigned msk = (tp < t) ? m_lt : ((tp == t) ? m_eq : m_gt);
                            cnt += __popc(em & msk);
                        }
                        val = (cnt < kkT) ? 1.0f : 0.0f;
                    }
                    rs[j] = val;
                }
                f32x4 rr; rr.x = rs[0]; rr.y = rs[1]; rr.z = rs[2]; rr.w = rs[3];
                __builtin_nontemporal_store(rr, o + it * BLK + t);
            }
            __syncthreads();   // protect sm reuse by next row
            if (row + 1 < ROWS) {   // restore pipeline: load next row
                const uint4* xin = reinterpret_cast<const uint4*>(x + (r0 + row + 1) * E);
                #pragma unroll
                for (int it = 0; it < PER; ++it) buf[it] = xin[it * BLK + t];
            }
        }
    }
}

extern "C" void kernel_launch(void* const* d_in, const int* in_sizes, int n_in,
                              void* d_out, int out_size, void* d_ws, size_t ws_size,
                              hipStream_t stream) {
    const float* x = (const float*)d_in[0];
    float* out = (float*)d_out;
    const int rows = in_sizes[0] / E;           // 4096
    kwta_kernel<<<dim3(rows / ROWS), dim3(BLK), 0, stream>>>(x, out);
}

// Round 11
// 67.175 us; speedup vs baseline: 1.8092x; 1.0323x over previous
//
#include <hip/hip_runtime.h>

// K-winners-take-all: per row of [4096, 8192] f32, exactly k=410 largest -> 1.0.
// Ties at the k-th value broken by LOWER index (jax.lax.top_k stable semantics).
//
// R11: pipeline through LDS, not registers. R8/R9/R10 all hit the same codegen
// wall (VGPR pinned at 32 + scratch) trying to keep two row buffers in VGPRs.
// Here each row is staged in a 32 KB LDS buffer, double-buffered:
//   - LDS 70 KB/block -> 2 blocks/CU; launch_bounds(512,4) -> 128-VGPR budget,
//     spill impossible.
//   - Row r: issue row r+1's 4x global_load_dwordx4 into transit regs at row
//     start; hist pass reads LDS buf[cur]; after B1 the transit regs are
//     ds_written to buf[nxt] (compiler inserts the counted vmcnt) and freed;
//     scan/collect/write all read buf[cur].
//   - Hot barriers are lgkmcnt-only + s_barrier (no vmcnt drain, no
//     sched_barrier) so the prefetch loads stay in flight across them.
// Selection per row (identical math to R10): 256 monotone bins over bits>1.5f,
// per-wave redundant suffix scan + shfl-max broadcast, (key,idx) clist in the
// threshold bin, winner = lex rank (value desc, index asc) < kkb.
// Cold exact paths fully inline (never on N(0,1)): f2ord radix + eqmask.

#define E      8192
#define BLK    512
#define PER    4            // uint4 chunks per thread per row
#define ROWS   4            // 4096/4 = 1024 blocks
#define KACT   410
#define NBINS  256
#define SHIFTB 16
#define BASEB  0x3FC00000u  // bits of 1.5f
#define CCAP   64

typedef float f32x4 __attribute__((ext_vector_type(4)));

struct __align__(16) Sm {
    float    buf[2][E];      // 64 KB row staging (double buffer)
    unsigned hist[NBINS];    // 1 KB
    unsigned clk[CCAP];
    unsigned cli[CCAP];
    unsigned eqmask[BLK];    // cold path only
    unsigned wsum[8];        // cold path only
    unsigned cnum, prefix, kk;
};

// LDS-only barrier: orders all LDS ops block-wide, leaves global loads/stores
// in flight (plain __syncthreads drains vmcnt(0) -> kills the prefetch).
#define BAR_LGKM() do {                                   \
    asm volatile("s_waitcnt lgkmcnt(0)" ::: "memory");    \
    __builtin_amdgcn_s_barrier();                         \
    asm volatile("" ::: "memory");                        \
} while (0)

__device__ __forceinline__ unsigned f2ord(unsigned u) {
    return (u & 0x80000000u) ? ~u : (u | 0x80000000u);
}

__global__ __launch_bounds__(BLK, 4)
void kwta_kernel(const float* __restrict__ x, float* __restrict__ out) {
    __shared__ Sm sm;
    const int t    = threadIdx.x;
    const int lane = t & 63;
    const size_t r0 = (size_t)blockIdx.x * ROWS;

    // ---- prologue: stage row 0 into buf[0] ----
    {
        const uint4* xn = reinterpret_cast<const uint4*>(x + r0 * E);
        uint4 g0 = xn[0 * BLK + t], g1 = xn[1 * BLK + t];
        uint4 g2 = xn[2 * BLK + t], g3 = xn[3 * BLK + t];
        uint4* wb = reinterpret_cast<uint4*>(sm.buf[0]);
        wb[0 * BLK + t] = g0; wb[1 * BLK + t] = g1;
        wb[2 * BLK + t] = g2; wb[3 * BLK + t] = g3;
    }
    __syncthreads();

    #pragma unroll 1
    for (int row = 0; row < ROWS; ++row) {
        const int cur = row & 1, nxt = cur ^ 1;
        const size_t rowbase = (r0 + row) * (size_t)E;
        const uint4* lb = reinterpret_cast<const uint4*>(sm.buf[cur]);

        // A: zero hist/cnum (LDS writes, ordered by B0)
        if (t < NBINS) sm.hist[t] = 0u;
        if (t == 0) sm.cnum = 0u;

        // B: issue next row's loads into transit regs (in flight across barriers)
        uint4 g0, g1, g2, g3;
        const bool pf = (row + 1 < ROWS);
        if (pf) {
            const uint4* xn = reinterpret_cast<const uint4*>(x + (r0 + row + 1) * E);
            g0 = xn[0 * BLK + t]; g1 = xn[1 * BLK + t];
            g2 = xn[2 * BLK + t]; g3 = xn[3 * BLK + t];
        }
        BAR_LGKM();                                         // B0

        // C: histogram candidates (> 1.5) from LDS
        #pragma unroll
        for (int it = 0; it < PER; ++it) {
            uint4 v = lb[it * BLK + t];
            unsigned a[4] = {v.x, v.y, v.z, v.w};
            #pragma unroll
            for (int j = 0; j < 4; ++j) {
                if (__uint_as_float(a[j]) > 1.5f) {
                    unsigned bb = (a[j] - BASEB) >> SHIFTB;
                    bb = (bb > NBINS - 1u) ? (NBINS - 1u) : bb;
                    atomicAdd(&sm.hist[bb], 1u);
                }
            }
        }
        BAR_LGKM();                                         // B1

        // D: retire transit regs into buf[nxt] (compiler emits counted vmcnt)
        if (pf) {
            uint4* wb = reinterpret_cast<uint4*>(sm.buf[nxt]);
            wb[0 * BLK + t] = g0; wb[1 * BLK + t] = g1;
            wb[2 * BLK + t] = g2; wb[3 * BLK + t] = g3;
        }

        // E: per-wave redundant suffix scan over 256 bins
        uint4 hv = reinterpret_cast<const uint4*>(sm.hist)[lane];
        unsigned h[4] = {hv.x, hv.y, hv.z, hv.w};
        unsigned local = h[0] + h[1] + h[2] + h[3];
        unsigned run = local;
        #pragma unroll
        for (int d = 1; d < 64; d <<= 1) {
            unsigned o = __shfl_down(run, d);
            run += (lane + d < 64) ? o : 0u;
        }
        const unsigned total = __shfl(run, 0);
        const unsigned tail  = run - local;
        unsigned bsel = 0, kkb = 0;
        {
            unsigned suf = tail;
            #pragma unroll
            for (int j2 = 3; j2 >= 0; --j2) {
                if (suf < KACT && suf + h[j2] >= KACT) { bsel = 4u * lane + j2; kkb = KACT - suf; }
                suf += h[j2];
            }
        }
        unsigned packed = kkb ? ((bsel << 16) | kkb) : 0u;   // one lane nonzero
        #pragma unroll
        for (int d = 1; d < 64; d <<= 1) {
            unsigned o = __shfl_xor(packed, d);
            packed = (o > packed) ? o : packed;
        }
        bsel = packed >> 16; kkb = packed & 0xFFFFu;

        const unsigned binlo = BASEB + (bsel << SHIFTB);
        const float binlo_f = __uint_as_float(binlo);
        const float binhi_f = (bsel == NBINS - 1u) ? __uint_as_float(0x7F800000u)
                                                   : __uint_as_float(binlo + (1u << SHIFTB));

        bool need_fb = (total < KACT);   // block-uniform
        if (!need_fb) {
            // F: collect threshold-bin (key, idx)
            #pragma unroll
            for (int it = 0; it < PER; ++it) {
                uint4 v = lb[it * BLK + t];
                unsigned a[4] = {v.x, v.y, v.z, v.w};
                #pragma unroll
                for (int j = 0; j < 4; ++j) {
                    float xf = __uint_as_float(a[j]);
                    if (xf > 1.5f && xf >= binlo_f && xf < binhi_f) {
                        unsigned p = atomicAdd(&sm.cnum, 1u);
                        if (p < CCAP) { sm.clk[p] = a[j]; sm.cli[p] = (unsigned)((it * BLK + t) * 4 + j); }
                    }
                }
            }
            BAR_LGKM();                                     // B2
            const unsigned cn = sm.cnum;
            if (cn <= CCAP) {
                // G: write mask from LDS values
                f32x4* o = reinterpret_cast<f32x4*>(out + rowbase);
                #pragma unroll
                for (int it = 0; it < PER; ++it) {
                    uint4 v = lb[it * BLK + t];
                    unsigned a[4] = {v.x, v.y, v.z, v.w};
                    float rs[4];
                    #pragma unroll
                    for (int j = 0; j < 4; ++j) {
                        unsigned key = a[j];
                        float xf = __uint_as_float(key);
                        float val;
                        if (xf >= binhi_f) val = 1.0f;
                        else if (xf > 1.5f && xf >= binlo_f) {
                            unsigned idx = (unsigned)((it * BLK + t) * 4 + j);
                            unsigned rank = 0;
                            for (unsigned q = 0; q < cn; ++q) {
                                unsigned kq = sm.clk[q];
                                rank += (kq > key || (kq == key && sm.cli[q] < idx)) ? 1u : 0u;
                            }
                            val = (rank < kkb) ? 1.0f : 0.0f;
                        } else val = 0.0f;
                        rs[j] = val;
                    }
                    f32x4 rr; rr.x = rs[0]; rr.y = rs[1]; rr.z = rs[2]; rr.w = rs[3];
                    __builtin_nontemporal_store(rr, o + it * BLK + t);
                }
            } else {
                need_fb = true;   // block-uniform
            }
        }

        if (need_fb) {
            // ======== COLD exact path (never on N(0,1)), fully inline ========
            __syncthreads();   // prior hist readers done; also drains safely
            if (t == 0) { sm.prefix = 0u; sm.kk = KACT; }

            #pragma unroll 1
            for (int p = 0; p < 4; ++p) {
                const int shift = 24 - 8 * p;
                const unsigned fixedmask = (p == 0) ? 0u : (0xFFFFFFFFu << (shift + 8));
                if (t < 256) sm.hist[t] = 0u;
                __syncthreads();
                const unsigned pref = sm.prefix;
                #pragma unroll
                for (int it = 0; it < PER; ++it) {
                    uint4 v = lb[it * BLK + t];
                    unsigned a[4] = {v.x, v.y, v.z, v.w};
                    #pragma unroll
                    for (int j = 0; j < 4; ++j) {
                        unsigned key = f2ord(a[j]);
                        if ((key & fixedmask) == pref)
                            atomicAdd(&sm.hist[(key >> shift) & 255u], 1u);
                    }
                }
                __syncthreads();
                if (t < 64) {
                    const int b4 = t * 4;
                    unsigned h0 = sm.hist[b4], h1 = sm.hist[b4 + 1];
                    unsigned h2 = sm.hist[b4 + 2], h3 = sm.hist[b4 + 3];
                    unsigned local2 = h0 + h1 + h2 + h3;
                    unsigned run2 = local2;
                    #pragma unroll
                    for (int d = 1; d < 64; d <<= 1) {
                        unsigned o = __shfl_down(run2, d);
                        run2 += (lane + d < 64) ? o : 0u;
                    }
                    const unsigned tail2 = run2 - local2;
                    const unsigned kk = sm.kk;
                    const unsigned s3 = tail2 + h3;
                    const unsigned s2 = s3 + h2;
                    const unsigned s1 = s2 + h1;
                    const unsigned s0 = s1 + h0;
                    if      (s0 >= kk && s1    < kk) { sm.prefix = pref | ((unsigned)(b4 + 0) << shift); sm.kk = kk - s1; }
                    else if (s1 >= kk && s2    < kk) { sm.prefix = pref | ((unsigned)(b4 + 1) << shift); sm.kk = kk - s2; }
                    else if (s2 >= kk && s3    < kk) { sm.prefix = pref | ((unsigned)(b4 + 2) << shift); sm.kk = kk - s3; }
                    else if (s3 >= kk && tail2 < kk) { sm.prefix = pref | ((unsigned)(b4 + 3) << shift); sm.kk = kk - tail2; }
                }
                __syncthreads();
            }
            const unsigned T = sm.prefix, kkT = sm.kk;

            unsigned myeq = 0u;
            #pragma unroll
            for (int it = 0; it < PER; ++it) {
                uint4 v = lb[it * BLK + t];
                unsigned a[4] = {v.x, v.y, v.z, v.w};
                #pragma unroll
                for (int j = 0; j < 4; ++j)
                    myeq |= (f2ord(a[j]) == T ? 1u : 0u) << (it * 4 + j);
            }
            sm.eqmask[t] = myeq;
            unsigned pm = __popc(myeq);
            #pragma unroll
            for (int d = 1; d < 64; d <<= 1) pm += __shfl_down(pm, d);
            if (lane == 0) sm.wsum[t >> 6] = pm;
            __syncthreads();
            unsigned m = 0;
            #pragma unroll
            for (int w = 0; w < 8; ++w) m += sm.wsum[w];
            const bool allwin = (kkT == m);

            f32x4* o = reinterpret_cast<f32x4*>(out + rowbase);
            #pragma unroll
            for (int it = 0; it < PER; ++it) {
                uint4 v = lb[it * BLK + t];
                unsigned a[4] = {v.x, v.y, v.z, v.w};
                float rs[4];
                #pragma unroll
                for (int j = 0; j < 4; ++j) {
                    unsigned key = f2ord(a[j]);
                    float val;
                    if (key > T)       val = 1.0f;
                    else if (key != T) val = 0.0f;
                    else if (allwin)   val = 1.0f;
                    else {
                        const unsigned m_lt = (2u << (4 * it + 3)) - 1u;
                        const unsigned m_eq = (1u << (4 * it + j)) - 1u;
                        const unsigned m_gt = (1u << (4 * it)) - 1u;
                        unsigned cnt = 0;
                        for (int tp = 0; tp < BLK; ++tp) {
                            unsigned em = sm.eqmask[tp];
                            unsigned msk = (tp < t) ? m_lt : ((tp == t) ? m_eq : m_gt);
                            cnt += __popc(em & msk);
                        }
                        val = (cnt < kkT) ? 1.0f : 0.0f;
                    }
                    rs[j] = val;
                }
                f32x4 rr; rr.x = rs[0]; rr.y = rs[1]; rr.z = rs[2]; rr.w = rs[3];
                __builtin_nontemporal_store(rr, o + it * BLK + t);
            }
        }

        // B3: all reads of buf[cur] done; buf[nxt] ds_writes visible block-wide
        BAR_LGKM();
    }
}

extern "C" void kernel_launch(void* const* d_in, const int* in_sizes, int n_in,
                              void* d_out, int out_size, void* d_ws, size_t ws_size,
                              hipStream_t stream) {
    const float* x = (const float*)d_in[0];
    float* out = (float*)d_out;
    const int rows = in_sizes[0] / E;           // 4096
    kwta_kernel<<<dim3(rows / ROWS), dim3(BLK), 0, stream>>>(x, out);
}

// Round 12
// 44.295 us; speedup vs baseline: 2.7437x; 1.5165x over previous
//
#include <hip/hip_runtime.h>

// K-winners-take-all: per row of [4096, 8192] f32, exactly k=410 largest -> 1.0.
// Ties at the k-th value broken by LOWER index (jax.lax.top_k stable semantics).
//
// FINAL (= R7, the measured optimum at 44.4 us = 96% of the 6.29 TB/s mixed
// R+W copy ceiling for the mandatory 268 MB of traffic).
// 512 threads/block, 16 elems/thread in registers (kv[4] x uint4),
// launch_bounds(512,8). One histogram pass over 512 monotone bins of the raw
// bits of candidates (x > 1.5; N(0,1) rows have ~547 >= k=410, 21-sigma margin),
// per-wave redundant suffix-scan + shfl-max broadcast of (threshold bin, kkb),
// (key,index) clist for the threshold bin, winner = lex-rank(value desc, index
// asc) < kkb -- handles unique k-th AND ties exactly in one code path.
// Exact fallbacks (never taken on N(0,1) data): f2ord block radix + eqmask.
//
// Lessons encoded here (R3/R8-R11): never clamp VGPR below the row footprint
// (spill doubles HBM traffic); register/LDS intra-block pipelining loses to
// plain TLP at high occupancy on this memory-bound op.

#define E      8192
#define BLK    512
#define PER    4            // uint4 per thread
#define KACT   410
#define NBINS  512
#define SHIFTB 15
#define BASEB  0x3FC00000u  // bits of 1.5f
#define CCAP   64

typedef float f32x4 __attribute__((ext_vector_type(4)));

__device__ __forceinline__ unsigned f2ord(unsigned u) {
    return (u & 0x80000000u) ? ~u : (u | 0x80000000u);
}

// fallback-only: rank of equal-element (it,j) of thread t among all equals.
// element index e = (it*BLK + t)*4 + j ; eqmask[t'] bit (it'*4+j') marks equals.
__device__ __noinline__ unsigned eq_rank(const unsigned* eqmask, int t, int it, int j) {
    const unsigned m_lt = (2u << (4 * it + 3)) - 1u;   // groups <= it fully
    const unsigned m_eq = (1u << (4 * it + j)) - 1u;   // own bits below (it,j)
    const unsigned m_gt = (1u << (4 * it)) - 1u;       // groups < it only
    unsigned cnt = 0;
    for (int tp = 0; tp < BLK; ++tp) {
        unsigned em = eqmask[tp];
        unsigned msk = (tp < t) ? m_lt : ((tp == t) ? m_eq : m_gt);
        cnt += __popc(em & msk);
    }
    return cnt;
}

__global__ __launch_bounds__(BLK, 8)
void kwta_kernel(const float* __restrict__ x, float* __restrict__ out) {
    __shared__ unsigned hist[NBINS];     // 2 KB
    __shared__ unsigned clk[CCAP];       // threshold-bin keys
    __shared__ unsigned cli[CCAP];       // threshold-bin indices
    __shared__ unsigned eqmask[BLK];     // fallback only (2 KB)
    __shared__ unsigned wsum[8];         // fallback only
    __shared__ unsigned s_cnum, s_prefix, s_kk;

    const int t    = threadIdx.x;
    const int lane = t & 63;
    const size_t rowbase = (size_t)blockIdx.x * (size_t)E;
    const uint4* xin = reinterpret_cast<const uint4*>(x + rowbase);

    // issue row loads first; they fly while we zero the histogram
    uint4 kv[PER];
    #pragma unroll
    for (int it = 0; it < PER; ++it) kv[it] = xin[it * BLK + t];

    if (t < NBINS) hist[t] = 0u;
    if (t == 0) { s_cnum = 0u; s_prefix = 0u; s_kk = KACT; }
    __syncthreads();                                            // B0

    // ---- histogram candidates (> 1.5) from registers ----
    #pragma unroll
    for (int it = 0; it < PER; ++it) {
        uint4 v = kv[it];
        unsigned a[4] = {v.x, v.y, v.z, v.w};
        #pragma unroll
        for (int j = 0; j < 4; ++j) {
            if (__uint_as_float(a[j]) > 1.5f) {
                unsigned bb = (a[j] - BASEB) >> SHIFTB;
                bb = (bb > NBINS - 1u) ? (NBINS - 1u) : bb;
                atomicAdd(&hist[bb], 1u);
            }
        }
    }
    __syncthreads();                                            // B1

    // ---- per-wave full suffix-scan of all 512 bins (redundant per wave) ----
    unsigned h[8]; unsigned local = 0;
    #pragma unroll
    for (int j2 = 0; j2 < 8; ++j2) { h[j2] = hist[8 * lane + j2]; local += h[j2]; }
    unsigned run = local;
    #pragma unroll
    for (int d = 1; d < 64; d <<= 1) {
        unsigned o = __shfl_down(run, d);
        run += (lane + d < 64) ? o : 0u;
    }
    const unsigned total = __shfl(run, 0);     // all candidates (> 1.5)
    const unsigned tail  = run - local;        // suffix over higher lanes
    unsigned bsel = 0, kkb = 0;
    {
        unsigned suf = tail;
        #pragma unroll
        for (int j2 = 7; j2 >= 0; --j2) {      // suf = count in bins > (8*lane+j2)
            if (suf < KACT && suf + h[j2] >= KACT) { bsel = 8u * lane + j2; kkb = KACT - suf; }
            suf += h[j2];
        }
    }
    unsigned packed = kkb ? ((bsel << 16) | kkb) : 0u;   // exactly one lane nonzero
    #pragma unroll
    for (int d = 1; d < 64; d <<= 1) {
        unsigned o = __shfl_xor(packed, d);
        packed = (o > packed) ? o : packed;
    }
    bsel = packed >> 16; kkb = packed & 0xFFFFu;

    bool fb = (total < KACT);   // threshold could be <= 1.5 -> exact fallback

    const unsigned binlo = BASEB + (bsel << SHIFTB);
    const float binlo_f = __uint_as_float(binlo);
    const float binhi_f = (bsel == NBINS - 1u) ? __uint_as_float(0x7F800000u)  // +inf
                                               : __uint_as_float(binlo + (1u << SHIFTB));

    // ---- collect threshold-bin (key, index) pairs ----
    if (!fb) {
        #pragma unroll
        for (int it = 0; it < PER; ++it) {
            uint4 v = kv[it];
            unsigned a[4] = {v.x, v.y, v.z, v.w};
            #pragma unroll
            for (int j = 0; j < 4; ++j) {
                float xf = __uint_as_float(a[j]);
                if (xf >= binlo_f && xf < binhi_f && xf > 1.5f) {
                    unsigned p = atomicAdd(&s_cnum, 1u);
                    if (p < CCAP) { clk[p] = a[j]; cli[p] = (unsigned)((it * BLK + t) * 4 + j); }
                }
            }
        }
    }
    __syncthreads();                                            // B2
    const unsigned cn = s_cnum;
    if (cn > CCAP) fb = true;   // adversarial pile-up -> exact fallback

    if (!fb) {
        // ---- fast path: winners = (x >= binhi) | (in-bin lex-rank < kkb) ----
        f32x4* o = reinterpret_cast<f32x4*>(out + rowbase);
        #pragma unroll
        for (int it = 0; it < PER; ++it) {
            uint4 v = kv[it];
            unsigned a[4] = {v.x, v.y, v.z, v.w};
            float rs[4];
            #pragma unroll
            for (int j = 0; j < 4; ++j) {
                unsigned key = a[j];
                float xf = __uint_as_float(key);
                float val;
                if (xf >= binhi_f) val = 1.0f;
                else if (xf >= binlo_f) {
                    // in threshold bin (rare: ~4-8 elements/row total)
                    unsigned idx = (unsigned)((it * BLK + t) * 4 + j);
                    unsigned rank = 0;
                    for (unsigned q = 0; q < cn; ++q) {
                        unsigned kq = clk[q];
                        rank += (kq > key || (kq == key && cli[q] < idx)) ? 1u : 0u;
                    }
                    val = (rank < kkb) ? 1.0f : 0.0f;
                } else val = 0.0f;
                rs[j] = val;
            }
            f32x4 rr; rr.x = rs[0]; rr.y = rs[1]; rr.z = rs[2]; rr.w = rs[3];
            __builtin_nontemporal_store(rr, o + it * BLK + t);
        }
        return;
    }

    // ---- exact fallback (never on this data): 4x8-bit f2ord radix + eqmask ----
    #pragma unroll 1
    for (int p = 0; p < 4; ++p) {
        const int shift = 24 - 8 * p;
        const unsigned fixedmask = (p == 0) ? 0u : (0xFFFFFFFFu << (shift + 8));
        if (t < 256) hist[t] = 0u;
        __syncthreads();
        const unsigned pref = s_prefix;
        #pragma unroll
        for (int it = 0; it < PER; ++it) {
            uint4 v = kv[it];
            unsigned a[4] = {v.x, v.y, v.z, v.w};
            #pragma unroll
            for (int j = 0; j < 4; ++j) {
                unsigned key = f2ord(a[j]);
                if ((key & fixedmask) == pref)
                    atomicAdd(&hist[(key >> shift) & 255u], 1u);
            }
        }
        __syncthreads();
        if (t < 64) {
            const int b4 = t * 4;
            unsigned h0 = hist[b4], h1 = hist[b4 + 1], h2 = hist[b4 + 2], h3 = hist[b4 + 3];
            unsigned local2 = h0 + h1 + h2 + h3;
            unsigned run2 = local2;
            #pragma unroll
            for (int d = 1; d < 64; d <<= 1) {
                unsigned o = __shfl_down(run2, d);
                run2 += (lane + d < 64) ? o : 0u;
            }
            const unsigned tail2 = run2 - local2;
            const unsigned kk = s_kk;
            const unsigned s3 = tail2 + h3;
            const unsigned s2 = s3 + h2;
            const unsigned s1 = s2 + h1;
            const unsigned s0 = s1 + h0;
            if      (s0 >= kk && s1    < kk) { s_prefix = pref | ((unsigned)(b4 + 0) << shift); s_kk = kk - s1; }
            else if (s1 >= kk && s2    < kk) { s_prefix = pref | ((unsigned)(b4 + 1) << shift); s_kk = kk - s2; }
            else if (s2 >= kk && s3    < kk) { s_prefix = pref | ((unsigned)(b4 + 2) << shift); s_kk = kk - s3; }
            else if (s3 >= kk && tail2 < kk) { s_prefix = pref | ((unsigned)(b4 + 3) << shift); s_kk = kk - tail2; }
        }
        __syncthreads();
    }
    const unsigned T = s_prefix, kkT = s_kk;

    unsigned myeq = 0u;
    #pragma unroll
    for (int it = 0; it < PER; ++it) {
        uint4 v = kv[it];
        unsigned a[4] = {v.x, v.y, v.z, v.w};
        #pragma unroll
        for (int j = 0; j < 4; ++j)
            myeq |= (f2ord(a[j]) == T ? 1u : 0u) << (it * 4 + j);
    }
    eqmask[t] = myeq;
    unsigned pm = __popc(myeq);
    #pragma unroll
    for (int d = 1; d < 64; d <<= 1) pm += __shfl_down(pm, d);
    if (lane == 0) wsum[t >> 6] = pm;
    __syncthreads();
    unsigned m = 0;
    #pragma unroll
    for (int w = 0; w < 8; ++w) m += wsum[w];
    const bool allwin = (kkT == m);

    f32x4* o = reinterpret_cast<f32x4*>(out + rowbase);
    #pragma unroll
    for (int it = 0; it < PER; ++it) {
        uint4 v = kv[it];
        unsigned a[4] = {v.x, v.y, v.z, v.w};
        float rs[4];
        #pragma unroll
        for (int j = 0; j < 4; ++j) {
            unsigned key = f2ord(a[j]);
            float val;
            if (key > T)       val = 1.0f;
            else if (key != T) val = 0.0f;
            else if (allwin)   val = 1.0f;
            else               val = (eq_rank(eqmask, t, it, j) < kkT) ? 1.0f : 0.0f;
            rs[j] = val;
        }
        f32x4 rr; rr.x = rs[0]; rr.y = rs[1]; rr.z = rs[2]; rr.w = rs[3];
        __builtin_nontemporal_store(rr, o + it * BLK + t);
    }
}

extern "C" void kernel_launch(void* const* d_in, const int* in_sizes, int n_in,
                              void* d_out, int out_size, void* d_ws, size_t ws_size,
                              hipStream_t stream) {
    const float* x = (const float*)d_in[0];
    float* out = (float*)d_out;
    const int rows = in_sizes[0] / E;   // 4096
    kwta_kernel<<<dim3(rows), dim3(BLK), 0, stream>>>(x, out);
}